// Round 4
// baseline (1773.661 us; speedup 1.0000x reference)
//
#include <hip/hip_runtime.h>
#include <hip/hip_bf16.h>

typedef unsigned short ushort_t;
typedef unsigned int uint_t;

#define BB 16
#define TE 128
#define TD 64
#define HH 256
#define G3 768
#define KK 256
#define OUTV 32000
#define MROWS_E (BB*TE)   // 2048
#define MROWS_D (BB*TD)   // 1024

typedef __attribute__((ext_vector_type(8))) short short8;
typedef __attribute__((ext_vector_type(4))) float f32x4;

__device__ __forceinline__ float b2f(ushort_t u) {
  union { uint_t i; float f; } v; v.i = ((uint_t)u) << 16; return v.f;
}
__device__ __forceinline__ ushort_t f2b(float f) {
  union { float f; uint_t i; } v; v.f = f;
  uint_t x = v.i;
  return (ushort_t)((x + 0x7fffu + ((x >> 16) & 1u)) >> 16);
}
__device__ __forceinline__ float blo(uint_t u){ union{uint_t i; float f;} v; v.i = u << 16; return v.f; }
__device__ __forceinline__ float bhi(uint_t u){ union{uint_t i; float f;} v; v.i = u & 0xffff0000u; return v.f; }
// dtype-adaptive scalar load of a "float" input: f32f!=0 -> fp32 buffer, else bf16
__device__ __forceinline__ float ldf(const void* p, size_t i, uint_t f32f) {
  return f32f ? ((const float*)p)[i] : b2f(((const ushort_t*)p)[i]);
}

// ---------------------------------------------------------------------------
// dtype detector: look at bits[14:7] of the first 256 words of `embedding`.
// bf16 pairs -> low element's exponent field, ~always in [100,127].
// fp32 -> random mantissa bits, ~11% in range. Writes 1 for fp32, 0 for bf16.
// (Round 1 vs 2 A/B proved flag=1 on this harness: inputs are fp32.)
// ---------------------------------------------------------------------------
__global__ __launch_bounds__(256) void detect_kernel(const void* emb, uint_t* flag) {
  int tid = threadIdx.x;
  uint_t w = ((const uint_t*)emb)[tid];
  uint_t e = (w >> 7) & 0xFFu;
  bool pass = (e >= 100u && e <= 127u);
  unsigned long long m = __ballot(pass);
  __shared__ int cnt[4];
  if ((tid & 63) == 0) cnt[tid >> 6] = __popcll(m);
  __syncthreads();
  if (tid == 0) {
    int c = cnt[0] + cnt[1] + cnt[2] + cnt[3];
    *flag = (c >= 128) ? 0u : 1u;
  }
}

// ---------------------------------------------------------------------------
// prep: pack Whh into per-k-pair gate-triple uints (bf16x2) for the recurrence;
// transpose dense_W to bf16 for coalesced reads in the attention kernel.
// WP[(kp*HH + j)*3 + g] = pack(Whh[g*HH+j][2kp], Whh[g*HH+j][2kp+1])
// DWT[k*HH + c] = dense_W[c*512 + k]
// ---------------------------------------------------------------------------
__global__ __launch_bounds__(256) void prep_kernel(
    const void* eWhh, const void* dWhh, const void* denseW,
    const uint_t* flagp, uint_t* WPe, uint_t* WPd, ushort_t* DWT) {
  uint_t f = *flagp;
  int tid = blockIdx.x * blockDim.x + threadIdx.x;
  int nth = gridDim.x * blockDim.x;
  for (int i = tid; i < 128*HH*3; i += nth) {
    int g = i % 3;
    int j = (i / 3) % HH;
    int kp = i / (3*HH);
    size_t r = (size_t)(g*HH + j) * KK;
    uint_t lo = f2b(ldf(eWhh, r + 2*kp, f));
    uint_t hi = f2b(ldf(eWhh, r + 2*kp + 1, f));
    WPe[i] = lo | (hi << 16);
    lo = f2b(ldf(dWhh, r + 2*kp, f));
    hi = f2b(ldf(dWhh, r + 2*kp + 1, f));
    WPd[i] = lo | (hi << 16);
  }
  for (int i = tid; i < 512*HH; i += nth) {
    int k = i / HH, c = i % HH;
    DWT[i] = f2b(ldf(denseW, (size_t)c*512 + k, f));
  }
}

// ---------------------------------------------------------------------------
// Generic MFMA GEMM: C[m][n] = sum_k A[m][k]*B[n][k] (+bias[n]), K=256 fixed.
// A rows: bf16 ws matrix, or gathered embedding rows (tokens!=null, dtype per
// flag); B: an input matrix (dtype per flag), converted to bf16 at LDS stage.
// Block covers 64 N-cols (grid.x); M looped in 32-row chunks strided grid.y.
// MFMA core restored (round 2/3 identical-error A/B exonerated the layout).
// ---------------------------------------------------------------------------
#define LDT 264

__global__ __launch_bounds__(256) void gemm_kernel(
    const ushort_t* A, const int* tokens, const void* emb,
    const void* Bw, int ldb, int b_off,
    const void* bias, const uint_t* flagp,
    float* Cf, ushort_t* Cb, int ldc, int M) {
  __shared__ __align__(16) ushort_t Bs[64*LDT];
  __shared__ __align__(16) ushort_t As[32*LDT];
  uint_t f = *flagp;
  int tid = threadIdx.x;
  int wave = tid >> 6, lane = tid & 63;
  int n0 = blockIdx.x * 64;
#pragma unroll
  for (int it = 0; it < 8; ++it) {
    int idx = it*256 + tid;
    int row = idx >> 5, col = (idx & 31) << 3;
    size_t e = (size_t)(n0 + row)*ldb + col + b_off;
    uint4 v;
    if (f) {
      const float4* s = (const float4*)((const float*)Bw + e);
      float4 x = s[0], y = s[1];
      v.x = (uint_t)f2b(x.x) | ((uint_t)f2b(x.y) << 16);
      v.y = (uint_t)f2b(x.z) | ((uint_t)f2b(x.w) << 16);
      v.z = (uint_t)f2b(y.x) | ((uint_t)f2b(y.y) << 16);
      v.w = (uint_t)f2b(y.z) | ((uint_t)f2b(y.w) << 16);
    } else {
      v = *(const uint4*)((const ushort_t*)Bw + e);
    }
    *(uint4*)(Bs + row*LDT + col) = v;
  }
  int arow_i = lane & 15;
  float bias_v = 0.f;
  if (bias) bias_v = ldf(bias, n0 + wave*16 + arow_i, f);
  int koff = (lane >> 4) << 3;
  for (int m0 = blockIdx.y*32; m0 < M; m0 += gridDim.y*32) {
    __syncthreads();   // Bs ready / previous chunk compute done
#pragma unroll
    for (int it = 0; it < 4; ++it) {
      int idx = it*256 + tid;
      int row = idx >> 5, col = (idx & 31) << 3;
      uint4 v;
      if (tokens) {
        size_t e = (size_t)tokens[m0 + row]*KK + col;
        if (f) {
          const float4* s = (const float4*)((const float*)emb + e);
          float4 x = s[0], y = s[1];
          v.x = (uint_t)f2b(x.x) | ((uint_t)f2b(x.y) << 16);
          v.y = (uint_t)f2b(x.z) | ((uint_t)f2b(x.w) << 16);
          v.z = (uint_t)f2b(y.x) | ((uint_t)f2b(y.y) << 16);
          v.w = (uint_t)f2b(y.z) | ((uint_t)f2b(y.w) << 16);
        } else {
          v = *(const uint4*)((const ushort_t*)emb + e);
        }
      } else {
        v = *(const uint4*)(A + (size_t)(m0 + row)*KK + col);  // ws bf16, always
      }
      *(uint4*)(As + row*LDT + col) = v;
    }
    __syncthreads();
#pragma unroll
    for (int msub = 0; msub < 2; ++msub) {
      f32x4 acc = {0.f,0.f,0.f,0.f};
      const ushort_t* ap = As + (msub*16 + arow_i)*LDT + koff;
      const ushort_t* bp = Bs + (wave*16 + arow_i)*LDT + koff;
#pragma unroll
      for (int ks = 0; ks < 8; ++ks) {
        short8 af = *(const short8*)(ap + ks*32);
        short8 bf = *(const short8*)(bp + ks*32);
        acc = __builtin_amdgcn_mfma_f32_16x16x32_bf16(af, bf, acc, 0, 0, 0);
      }
      int mbase = m0 + msub*16 + (lane >> 4)*4;
      int ncol = n0 + wave*16 + arow_i;
#pragma unroll
      for (int r = 0; r < 4; ++r) {
        float val = acc[r] + bias_v;
        if (Cf) Cf[(size_t)(mbase + r)*ldc + ncol] = val;
        else    Cb[(size_t)(mbase + r)*ldc + ncol] = f2b(val);
      }
    }
  }
}

// ---------------------------------------------------------------------------
// GRU recurrence: one block per sample, thread j owns hidden column j.
// h (fp32) in LDS; Whh streamed as packed bf16 pairs (gate-triple layout).
// Encoder then decoder in the same kernel (h carries over).
// ---------------------------------------------------------------------------
__device__ void gru_phase(float* h, const float* gi, const uint_t* WP,
                          const void* bhh, uint_t f, int len, int T,
                          float* out, ushort_t* out_bf, int j) {
  float br = ldf(bhh, j, f), bz = ldf(bhh, HH+j, f), bn = ldf(bhh, 2*HH+j, f);
  for (int t = 0; t < T; ++t) {
    float ar = 0.f, az = 0.f, an = 0.f;
    const uint_t* w = WP + j*3;
#pragma unroll 4
    for (int kp = 0; kp < HH/2; ++kp) {
      uint_t u0 = w[0], u1 = w[1], u2 = w[2];
      float h0 = h[2*kp], h1 = h[2*kp+1];
      ar = fmaf(blo(u0), h0, ar); ar = fmaf(bhi(u0), h1, ar);
      az = fmaf(blo(u1), h0, az); az = fmaf(bhi(u1), h1, az);
      an = fmaf(blo(u2), h0, an); an = fmaf(bhi(u2), h1, an);
      w += 3*HH;
    }
    const float* g = gi + (size_t)t*G3;
    float hj = h[j];
    float r = 1.f/(1.f + expf(-(g[j]      + ar + br)));
    float z = 1.f/(1.f + expf(-(g[HH+j]   + az + bz)));
    float n = tanhf(g[2*HH+j] + r*(an + bn));
    float hc = (1.f - z)*n + z*hj;
    bool valid = t < len;
    float ov = valid ? hc : 0.f;
    out[(size_t)t*HH + j] = ov;
    out_bf[(size_t)t*HH + j] = f2b(ov);
    float hnew = valid ? hc : hj;
    __syncthreads();
    h[j] = hnew;
    __syncthreads();
  }
}

__global__ __launch_bounds__(256) void gru_kernel(
    const float* gi_e, const float* gi_d, const uint_t* WPe, const uint_t* WPd,
    const void* ebhh, const void* dbhh, const uint_t* flagp,
    const int* elen, const int* dlen,
    float* eout, float* dout, ushort_t* eout_bf, ushort_t* dout_bf) {
  int b = blockIdx.x, j = threadIdx.x;
  uint_t f = *flagp;
  __shared__ float h[HH];
  h[j] = 0.f;
  __syncthreads();
  gru_phase(h, gi_e + (size_t)b*TE*G3, WPe, ebhh, f, elen[b], TE,
            eout + (size_t)b*TE*HH, eout_bf + (size_t)b*TE*HH, j);
  gru_phase(h, gi_d + (size_t)b*TD*G3, WPd, dbhh, f, dlen[b], TD,
            dout + (size_t)b*TD*HH, dout_bf + (size_t)b*TD*HH, j);
}

// ---------------------------------------------------------------------------
// Attention + dense, one block per (b, td).
// energy[te] = tanh(enc_proj+dec_proj+Wb)·v + vb for valid te; the unmasked
// softmax denominator cancels against the post-mask renormalization, so
// attention[te] = p[te]/sum_valid(p). Then context, then dense = tanh(...).
// ---------------------------------------------------------------------------
__global__ __launch_bounds__(256) void attn_kernel(
    const float* eprj, const float* dprj, const float* eout, const float* dout,
    const void* Wb, const void* av, const void* avb,
    const ushort_t* DWT, const void* db, const uint_t* flagp,
    const int* elen, const int* dlen, ushort_t* dense_bf) {
  int bd = blockIdx.x;
  int b = bd / TD, td = bd % TD;
  int tid = threadIdx.x;
  int wave = tid >> 6, lane = tid & 63;
  uint_t f = *flagp;
  __shared__ float dp[HH], dsrow[HH], vv[HH], att[TE];
  int el = elen[b];
  bool dok = td < dlen[b];
  size_t drow = (size_t)bd * HH;
  dp[tid] = dprj[drow + tid] + ldf(Wb, tid, f);
  dsrow[tid] = dout[drow + tid];
  vv[tid] = ldf(av, tid, f);
  __syncthreads();
  float vb0 = ldf(avb, 0, f);
  for (int teb = 0; teb < TE/4; ++teb) {
    int te = teb*4 + wave;
    float e = -1e30f;
    if (dok && te < el) {
      const float* ep = eprj + (size_t)(b*TE + te)*HH;
      float s = 0.f;
#pragma unroll
      for (int i = 0; i < 4; ++i) {
        int hh = lane + 64*i;
        s += tanhf(ep[hh] + dp[hh]) * vv[hh];
      }
#pragma unroll
      for (int off = 32; off > 0; off >>= 1) s += __shfl_xor(s, off);
      e = s + vb0;
    }
    if (lane == 0) att[te] = e;
  }
  __syncthreads();
  float m = -1e30f;
  for (int te = 0; te < TE; ++te) m = fmaxf(m, att[te]);
  __syncthreads();
  if (tid < TE) {
    float e = att[tid];
    att[tid] = (e > -1e29f) ? expf(e - m) : 0.f;
  }
  __syncthreads();
  float ssum = 0.f;
  for (int te = 0; te < TE; ++te) ssum += att[te];
  float inv = (ssum > 0.f) ? 1.f/ssum : 0.f;
  float c = 0.f;
  for (int te = 0; te < TE; ++te) {
    float wgt = att[te];
    if (wgt > 0.f) c += wgt * eout[(size_t)(b*TE + te)*HH + tid];
  }
  c *= inv;
  __syncthreads();
  dp[tid] = c;   // reuse dp as context
  __syncthreads();
  float acc = ldf(db, tid, f);
#pragma unroll 4
  for (int k = 0; k < HH; ++k) acc = fmaf(b2f(DWT[k*HH + tid]), dsrow[k], acc);
#pragma unroll 4
  for (int k = 0; k < HH; ++k) acc = fmaf(b2f(DWT[(HH + k)*HH + tid]), dp[k], acc);
  dense_bf[drow + tid] = f2b(tanhf(acc));
}

// ---------------------------------------------------------------------------
extern "C" void kernel_launch(void* const* d_in, const int* in_sizes, int n_in,
                              void* d_out, int out_size, void* d_ws, size_t ws_size,
                              hipStream_t stream) {
  const int* enc_in   = (const int*)d_in[0];
  const int* enc_len  = (const int*)d_in[1];
  const int* dec_in   = (const int*)d_in[2];
  const int* dec_len  = (const int*)d_in[3];
  const void* emb    = d_in[4];
  const void* eWih   = d_in[5];
  const void* eWhh   = d_in[6];
  const void* ebih   = d_in[7];
  const void* ebhh   = d_in[8];
  const void* dWih   = d_in[9];
  const void* dWhh   = d_in[10];
  const void* dbih   = d_in[11];
  const void* dbhh   = d_in[12];
  const void* attnW  = d_in[13];
  const void* attnWb = d_in[14];
  const void* attnv  = d_in[15];
  const void* attnvb = d_in[16];
  const void* denseW = d_in[17];
  const void* denseb = d_in[18];
  const void* outW   = d_in[19];
  const void* outb   = d_in[20];
  float* out = (float*)d_out;   // reference output is fp32 (inputs proved fp32)

  float* ws = (float*)d_ws;
  size_t o = 0;
  uint_t* flag = (uint_t*)(ws + o);   o += 4;
  uint_t* WPe = (uint_t*)(ws + o);    o += 128*HH*3;
  uint_t* WPd = (uint_t*)(ws + o);    o += 128*HH*3;
  ushort_t* DWT = (ushort_t*)(ws + o); o += 512*HH/2;
  float* gi_e = ws + o;               o += (size_t)MROWS_E*G3;
  float* gi_d = ws + o;               o += (size_t)MROWS_D*G3;
  float* eout = ws + o;               o += (size_t)MROWS_E*HH;
  float* dout = ws + o;               o += (size_t)MROWS_D*HH;
  ushort_t* eout_bf = (ushort_t*)(ws + o); o += (size_t)MROWS_E*HH/2;
  ushort_t* dout_bf = (ushort_t*)(ws + o); o += (size_t)MROWS_D*HH/2;
  float* eprj = ws + o;               o += (size_t)MROWS_E*HH;
  float* dprj = ws + o;               o += (size_t)MROWS_D*HH;
  ushort_t* dense_bf = (ushort_t*)(ws + o); o += (size_t)MROWS_D*HH/2;

  detect_kernel<<<1, 256, 0, stream>>>(emb, flag);
  prep_kernel<<<384, 256, 0, stream>>>(eWhh, dWhh, denseW, flag, WPe, WPd, DWT);
  // gi = emb[tokens] @ Wih.T + bih
  gemm_kernel<<<dim3(12,8), 256, 0, stream>>>(nullptr, enc_in, emb, eWih, 256, 0,
                                              ebih, flag, gi_e, nullptr, G3, MROWS_E);
  gemm_kernel<<<dim3(12,4), 256, 0, stream>>>(nullptr, dec_in, emb, dWih, 256, 0,
                                              dbih, flag, gi_d, nullptr, G3, MROWS_D);
  gru_kernel<<<BB, 256, 0, stream>>>(gi_e, gi_d, WPe, WPd, ebhh, dbhh, flag,
                                     enc_len, dec_len, eout, dout, eout_bf, dout_bf);
  // enc_proj = enc_out @ W1.T ; dec_proj = dec_out @ W2.T  (attn_W col split)
  gemm_kernel<<<dim3(4,16), 256, 0, stream>>>(eout_bf, nullptr, nullptr, attnW, 512, 0,
                                              nullptr, flag, eprj, nullptr, HH, MROWS_E);
  gemm_kernel<<<dim3(4,8), 256, 0, stream>>>(dout_bf, nullptr, nullptr, attnW, 512, 256,
                                             nullptr, flag, dprj, nullptr, HH, MROWS_D);
  attn_kernel<<<MROWS_D, 256, 0, stream>>>(eprj, dprj, eout, dout, attnWb, attnv, attnvb,
                                           DWT, denseb, flag, enc_len, dec_len, dense_bf);
  // logits = dense @ out_W.T + out_b  (fp32 out)
  gemm_kernel<<<dim3(500,4), 256, 0, stream>>>(dense_bf, nullptr, nullptr, outW, 256, 0,
                                               outb, flag, out, nullptr, OUTV, MROWS_D);
}

// Round 5
// 1681.770 us; speedup vs baseline: 1.0546x; 1.0546x over previous
//
#include <hip/hip_runtime.h>
#include <hip/hip_bf16.h>

typedef unsigned short ushort_t;
typedef unsigned int uint_t;

#define BB 16
#define TE 128
#define TD 64
#define HH 256
#define G3 768
#define KK 256
#define OUTV 32000
#define MROWS_E (BB*TE)   // 2048
#define MROWS_D (BB*TD)   // 1024

typedef __attribute__((ext_vector_type(8))) short short8;
typedef __attribute__((ext_vector_type(4))) float f32x4;

__device__ __forceinline__ float b2f(ushort_t u) {
  union { uint_t i; float f; } v; v.i = ((uint_t)u) << 16; return v.f;
}
__device__ __forceinline__ ushort_t f2b(float f) {
  union { float f; uint_t i; } v; v.f = f;
  uint_t x = v.i;
  return (ushort_t)((x + 0x7fffu + ((x >> 16) & 1u)) >> 16);
}
__device__ __forceinline__ float blo(uint_t u){ union{uint_t i; float f;} v; v.i = u << 16; return v.f; }
__device__ __forceinline__ float bhi(uint_t u){ union{uint_t i; float f;} v; v.i = u & 0xffff0000u; return v.f; }
// dtype-adaptive scalar load of a "float" input: f32f!=0 -> fp32 buffer, else bf16
__device__ __forceinline__ float ldf(const void* p, size_t i, uint_t f32f) {
  return f32f ? ((const float*)p)[i] : b2f(((const ushort_t*)p)[i]);
}
// fast, saturating sigmoid/tanh (inputs bounded; formulas robust at +-inf)
__device__ __forceinline__ float fsig(float x) { return 1.f/(1.f + __expf(-x)); }
__device__ __forceinline__ float ftanh(float x) { return 1.f - 2.f/(__expf(2.f*x) + 1.f); }

// ---------------------------------------------------------------------------
// dtype detector (round1/2 A/B proved fp32 on this harness; kept for safety).
// ---------------------------------------------------------------------------
__global__ __launch_bounds__(256) void detect_kernel(const void* emb, uint_t* flag) {
  int tid = threadIdx.x;
  uint_t w = ((const uint_t*)emb)[tid];
  uint_t e = (w >> 7) & 0xFFu;
  bool pass = (e >= 100u && e <= 127u);
  unsigned long long m = __ballot(pass);
  __shared__ int cnt[4];
  if ((tid & 63) == 0) cnt[tid >> 6] = __popcll(m);
  __syncthreads();
  if (tid == 0) {
    int c = cnt[0] + cnt[1] + cnt[2] + cnt[3];
    *flag = (c >= 128) ? 0u : 1u;
  }
}

// ---------------------------------------------------------------------------
// prep: Whh -> bf16 row-major [768][256] (MFMA B operand for the recurrence);
// dense_W -> bf16 transpose for the attention kernel.
// ---------------------------------------------------------------------------
__global__ __launch_bounds__(256) void prep_kernel(
    const void* eWhh, const void* dWhh, const void* denseW,
    const uint_t* flagp, ushort_t* WBe, ushort_t* WBd, ushort_t* DWT) {
  uint_t f = *flagp;
  int tid = blockIdx.x * blockDim.x + threadIdx.x;
  int nth = gridDim.x * blockDim.x;
  for (int i = tid; i < G3*KK; i += nth) {
    WBe[i] = f2b(ldf(eWhh, i, f));
    WBd[i] = f2b(ldf(dWhh, i, f));
  }
  for (int i = tid; i < 512*HH; i += nth) {
    int k = i / HH, c = i % HH;
    DWT[i] = f2b(ldf(denseW, (size_t)c*512 + k, f));
  }
}

// ---------------------------------------------------------------------------
// Generic MFMA GEMM: C[m][n] = sum_k A[m][k]*B[n][k] (+bias[n]), K=256 fixed.
// (unchanged from the round-4 passing version)
// ---------------------------------------------------------------------------
#define LDT 264

__global__ __launch_bounds__(256) void gemm_kernel(
    const ushort_t* A, const int* tokens, const void* emb,
    const void* Bw, int ldb, int b_off,
    const void* bias, const uint_t* flagp,
    float* Cf, ushort_t* Cb, int ldc, int M) {
  __shared__ __align__(16) ushort_t Bs[64*LDT];
  __shared__ __align__(16) ushort_t As[32*LDT];
  uint_t f = *flagp;
  int tid = threadIdx.x;
  int wave = tid >> 6, lane = tid & 63;
  int n0 = blockIdx.x * 64;
#pragma unroll
  for (int it = 0; it < 8; ++it) {
    int idx = it*256 + tid;
    int row = idx >> 5, col = (idx & 31) << 3;
    size_t e = (size_t)(n0 + row)*ldb + col + b_off;
    uint4 v;
    if (f) {
      const float4* s = (const float4*)((const float*)Bw + e);
      float4 x = s[0], y = s[1];
      v.x = (uint_t)f2b(x.x) | ((uint_t)f2b(x.y) << 16);
      v.y = (uint_t)f2b(x.z) | ((uint_t)f2b(x.w) << 16);
      v.z = (uint_t)f2b(y.x) | ((uint_t)f2b(y.y) << 16);
      v.w = (uint_t)f2b(y.z) | ((uint_t)f2b(y.w) << 16);
    } else {
      v = *(const uint4*)((const ushort_t*)Bw + e);
    }
    *(uint4*)(Bs + row*LDT + col) = v;
  }
  int arow_i = lane & 15;
  float bias_v = 0.f;
  if (bias) bias_v = ldf(bias, n0 + wave*16 + arow_i, f);
  int koff = (lane >> 4) << 3;
  for (int m0 = blockIdx.y*32; m0 < M; m0 += gridDim.y*32) {
    __syncthreads();   // Bs ready / previous chunk compute done
#pragma unroll
    for (int it = 0; it < 4; ++it) {
      int idx = it*256 + tid;
      int row = idx >> 5, col = (idx & 31) << 3;
      uint4 v;
      if (tokens) {
        size_t e = (size_t)tokens[m0 + row]*KK + col;
        if (f) {
          const float4* s = (const float4*)((const float*)emb + e);
          float4 x = s[0], y = s[1];
          v.x = (uint_t)f2b(x.x) | ((uint_t)f2b(x.y) << 16);
          v.y = (uint_t)f2b(x.z) | ((uint_t)f2b(x.w) << 16);
          v.z = (uint_t)f2b(y.x) | ((uint_t)f2b(y.y) << 16);
          v.w = (uint_t)f2b(y.z) | ((uint_t)f2b(y.w) << 16);
        } else {
          v = *(const uint4*)((const ushort_t*)emb + e);
        }
      } else {
        v = *(const uint4*)(A + (size_t)(m0 + row)*KK + col);  // ws bf16, always
      }
      *(uint4*)(As + row*LDT + col) = v;
    }
    __syncthreads();
#pragma unroll
    for (int msub = 0; msub < 2; ++msub) {
      f32x4 acc = {0.f,0.f,0.f,0.f};
      const ushort_t* ap = As + (msub*16 + arow_i)*LDT + koff;
      const ushort_t* bp = Bs + (wave*16 + arow_i)*LDT + koff;
#pragma unroll
      for (int ks = 0; ks < 8; ++ks) {
        short8 af = *(const short8*)(ap + ks*32);
        short8 bf = *(const short8*)(bp + ks*32);
        acc = __builtin_amdgcn_mfma_f32_16x16x32_bf16(af, bf, acc, 0, 0, 0);
      }
      int mbase = m0 + msub*16 + (lane >> 4)*4;
      int ncol = n0 + wave*16 + arow_i;
#pragma unroll
      for (int r = 0; r < 4; ++r) {
        float val = acc[r] + bias_v;
        if (Cf) Cf[(size_t)(mbase + r)*ldc + ncol] = val;
        else    Cb[(size_t)(mbase + r)*ldc + ncol] = f2b(val);
      }
    }
  }
}

// ---------------------------------------------------------------------------
// MFMA GRU: ONE block, 16 waves, whole batch. Whh B-fragments live in
// registers (96 VGPR/wave) for the entire recurrence. Wave w owns hidden
// cols j in [16w,16w+16) and computes the r/z/n gate rows for those j
// (Whh rows 16w / 256+16w / 512+16w), so after the 3-tile MFMA each lane
// holds all three gate pre-activations for (m=quad*4+r, j) -> gates are
// evaluated entirely in registers (no LDS round-trip for gh).
// h: fp32 master + bf16 mirror (MFMA A operand) in LDS. 2 barriers/step.
// ---------------------------------------------------------------------------
#define HS32 260   // h_f32 row stride (fp32), padded: <=2-way LDS aliasing
#define HSBF 264   // h_bf row stride (bf16), padded: <=2-way on b128 reads

__device__ __forceinline__ void gru_phase_mfma(
    const float* gi, const ushort_t* WB, const void* bhh, const int* lens,
    uint_t f, int T, float* out, ushort_t* out_bf,
    float* h_f32, ushort_t* h_bf, float* bhh_s, int* len_s)
{
  int tid = threadIdx.x;
  int wave = tid >> 6, lane = tid & 63;
  int mrow = lane & 15, quad = lane >> 4;
  if (tid < G3) bhh_s[tid] = ldf(bhh, tid, f);
  if (tid < BB) len_s[tid] = lens[tid];
  // B fragments: gate g tile = Whh rows [g*256 + 16*wave, +16), all K=256.
  short8 bfrag[3][8];
  const ushort_t* wb = WB + (size_t)((wave << 4) + mrow)*KK + (quad << 3);
#pragma unroll
  for (int g = 0; g < 3; ++g)
#pragma unroll
    for (int ks = 0; ks < 8; ++ks)
      bfrag[g][ks] = *(const short8*)(wb + (size_t)g*HH*KK + ks*32);
  __syncthreads();   // bhh_s/len_s staged; h state ready
  int j = (wave << 4) + mrow;
  for (int t = 0; t < T; ++t) {
    f32x4 a0 = {0.f,0.f,0.f,0.f}, a1 = {0.f,0.f,0.f,0.f}, a2 = {0.f,0.f,0.f,0.f};
    const ushort_t* hb = h_bf + mrow*HSBF + (quad << 3);
#pragma unroll
    for (int ks = 0; ks < 8; ++ks) {
      short8 av = *(const short8*)(hb + ks*32);
      a0 = __builtin_amdgcn_mfma_f32_16x16x32_bf16(av, bfrag[0][ks], a0, 0, 0, 0);
      a1 = __builtin_amdgcn_mfma_f32_16x16x32_bf16(av, bfrag[1][ks], a1, 0, 0, 0);
      a2 = __builtin_amdgcn_mfma_f32_16x16x32_bf16(av, bfrag[2][ks], a2, 0, 0, 0);
    }
    __syncthreads();   // all waves done reading h_bf
    float br = bhh_s[j], bz = bhh_s[HH + j], bn = bhh_s[2*HH + j];
#pragma unroll
    for (int r = 0; r < 4; ++r) {
      int m = (quad << 2) + r;
      const float* gp = gi + (size_t)(m*T + t)*G3 + j;
      float gir = gp[0], giz = gp[HH], gin = gp[2*HH];
      float rr = fsig(gir + a0[r] + br);
      float zz = fsig(giz + a1[r] + bz);
      float nn = ftanh(gin + rr*(a2[r] + bn));
      float hold = h_f32[m*HS32 + j];
      float hc = (1.f - zz)*nn + zz*hold;
      bool valid = t < len_s[m];
      float ov = valid ? hc : 0.f;
      float hnew = valid ? hc : hold;
      size_t oo = (size_t)(m*T + t)*HH + j;
      out[oo] = ov;
      out_bf[oo] = f2b(ov);
      h_f32[m*HS32 + j] = hnew;    // (m,j) owned by exactly this lane
      h_bf[m*HSBF + j] = f2b(hnew);
    }
    __syncthreads();   // h updated before next step's A-frag reads
  }
}

__global__ __launch_bounds__(1024, 4) void gru_kernel(
    const float* gi_e, const float* gi_d, const ushort_t* WBe, const ushort_t* WBd,
    const void* ebhh, const void* dbhh, const uint_t* flagp,
    const int* elen, const int* dlen,
    float* eout, float* dout, ushort_t* eout_bf, ushort_t* dout_bf) {
  uint_t f = *flagp;
  __shared__ __align__(16) float h_f32[BB*HS32];
  __shared__ __align__(16) ushort_t h_bf[BB*HSBF];
  __shared__ float bhh_s[G3];
  __shared__ int len_s[BB];
  int tid = threadIdx.x;
  for (int i = tid; i < BB*HS32; i += 1024) h_f32[i] = 0.f;
  for (int i = tid; i < BB*HSBF; i += 1024) h_bf[i] = 0;
  // (visibility covered by the barrier inside the phase)
  gru_phase_mfma(gi_e, WBe, ebhh, elen, f, TE, eout, eout_bf, h_f32, h_bf, bhh_s, len_s);
  gru_phase_mfma(gi_d, WBd, dbhh, dlen, f, TD, dout, dout_bf, h_f32, h_bf, bhh_s, len_s);
}

// ---------------------------------------------------------------------------
// Attention + dense, one block per (b, td). (unchanged from round 4)
// ---------------------------------------------------------------------------
__global__ __launch_bounds__(256) void attn_kernel(
    const float* eprj, const float* dprj, const float* eout, const float* dout,
    const void* Wb, const void* av, const void* avb,
    const ushort_t* DWT, const void* db, const uint_t* flagp,
    const int* elen, const int* dlen, ushort_t* dense_bf) {
  int bd = blockIdx.x;
  int b = bd / TD, td = bd % TD;
  int tid = threadIdx.x;
  int wave = tid >> 6, lane = tid & 63;
  uint_t f = *flagp;
  __shared__ float dp[HH], dsrow[HH], vv[HH], att[TE];
  int el = elen[b];
  bool dok = td < dlen[b];
  size_t drow = (size_t)bd * HH;
  dp[tid] = dprj[drow + tid] + ldf(Wb, tid, f);
  dsrow[tid] = dout[drow + tid];
  vv[tid] = ldf(av, tid, f);
  __syncthreads();
  float vb0 = ldf(avb, 0, f);
  for (int teb = 0; teb < TE/4; ++teb) {
    int te = teb*4 + wave;
    float e = -1e30f;
    if (dok && te < el) {
      const float* ep = eprj + (size_t)(b*TE + te)*HH;
      float s = 0.f;
#pragma unroll
      for (int i = 0; i < 4; ++i) {
        int hh = lane + 64*i;
        s += tanhf(ep[hh] + dp[hh]) * vv[hh];
      }
#pragma unroll
      for (int off = 32; off > 0; off >>= 1) s += __shfl_xor(s, off);
      e = s + vb0;
    }
    if (lane == 0) att[te] = e;
  }
  __syncthreads();
  float m = -1e30f;
  for (int te = 0; te < TE; ++te) m = fmaxf(m, att[te]);
  __syncthreads();
  if (tid < TE) {
    float e = att[tid];
    att[tid] = (e > -1e29f) ? expf(e - m) : 0.f;
  }
  __syncthreads();
  float ssum = 0.f;
  for (int te = 0; te < TE; ++te) ssum += att[te];
  float inv = (ssum > 0.f) ? 1.f/ssum : 0.f;
  float c = 0.f;
  for (int te = 0; te < TE; ++te) {
    float wgt = att[te];
    if (wgt > 0.f) c += wgt * eout[(size_t)(b*TE + te)*HH + tid];
  }
  c *= inv;
  __syncthreads();
  dp[tid] = c;   // reuse dp as context
  __syncthreads();
  float acc = ldf(db, tid, f);
#pragma unroll 4
  for (int k = 0; k < HH; ++k) acc = fmaf(b2f(DWT[k*HH + tid]), dsrow[k], acc);
#pragma unroll 4
  for (int k = 0; k < HH; ++k) acc = fmaf(b2f(DWT[(HH + k)*HH + tid]), dp[k], acc);
  dense_bf[drow + tid] = f2b(tanhf(acc));
}

// ---------------------------------------------------------------------------
extern "C" void kernel_launch(void* const* d_in, const int* in_sizes, int n_in,
                              void* d_out, int out_size, void* d_ws, size_t ws_size,
                              hipStream_t stream) {
  const int* enc_in   = (const int*)d_in[0];
  const int* enc_len  = (const int*)d_in[1];
  const int* dec_in   = (const int*)d_in[2];
  const int* dec_len  = (const int*)d_in[3];
  const void* emb    = d_in[4];
  const void* eWih   = d_in[5];
  const void* eWhh   = d_in[6];
  const void* ebih   = d_in[7];
  const void* ebhh   = d_in[8];
  const void* dWih   = d_in[9];
  const void* dWhh   = d_in[10];
  const void* dbih   = d_in[11];
  const void* dbhh   = d_in[12];
  const void* attnW  = d_in[13];
  const void* attnWb = d_in[14];
  const void* attnv  = d_in[15];
  const void* attnvb = d_in[16];
  const void* denseW = d_in[17];
  const void* denseb = d_in[18];
  const void* outW   = d_in[19];
  const void* outb   = d_in[20];
  float* out = (float*)d_out;   // reference output is fp32

  float* ws = (float*)d_ws;
  size_t o = 0;
  uint_t* flag = (uint_t*)(ws + o);   o += 4;
  ushort_t* WBe = (ushort_t*)(ws + o); o += G3*KK/2;   // 98304 floats
  ushort_t* WBd = (ushort_t*)(ws + o); o += G3*KK/2;
  ushort_t* DWT = (ushort_t*)(ws + o); o += 512*HH/2;
  float* gi_e = ws + o;               o += (size_t)MROWS_E*G3;
  float* gi_d = ws + o;               o += (size_t)MROWS_D*G3;
  float* eout = ws + o;               o += (size_t)MROWS_E*HH;
  float* dout = ws + o;               o += (size_t)MROWS_D*HH;
  ushort_t* eout_bf = (ushort_t*)(ws + o); o += (size_t)MROWS_E*HH/2;
  ushort_t* dout_bf = (ushort_t*)(ws + o); o += (size_t)MROWS_D*HH/2;
  float* eprj = ws + o;               o += (size_t)MROWS_E*HH;
  float* dprj = ws + o;               o += (size_t)MROWS_D*HH;
  ushort_t* dense_bf = (ushort_t*)(ws + o); o += (size_t)MROWS_D*HH/2;

  detect_kernel<<<1, 256, 0, stream>>>(emb, flag);
  prep_kernel<<<384, 256, 0, stream>>>(eWhh, dWhh, denseW, flag, WBe, WBd, DWT);
  // gi = emb[tokens] @ Wih.T + bih
  gemm_kernel<<<dim3(12,8), 256, 0, stream>>>(nullptr, enc_in, emb, eWih, 256, 0,
                                              ebih, flag, gi_e, nullptr, G3, MROWS_E);
  gemm_kernel<<<dim3(12,4), 256, 0, stream>>>(nullptr, dec_in, emb, dWih, 256, 0,
                                              dbih, flag, gi_d, nullptr, G3, MROWS_D);
  gru_kernel<<<1, 1024, 0, stream>>>(gi_e, gi_d, WBe, WBd, ebhh, dbhh, flag,
                                     enc_len, dec_len, eout, dout, eout_bf, dout_bf);
  // enc_proj = enc_out @ W1.T ; dec_proj = dec_out @ W2.T  (attn_W col split)
  gemm_kernel<<<dim3(4,16), 256, 0, stream>>>(eout_bf, nullptr, nullptr, attnW, 512, 0,
                                              nullptr, flag, eprj, nullptr, HH, MROWS_E);
  gemm_kernel<<<dim3(4,8), 256, 0, stream>>>(dout_bf, nullptr, nullptr, attnW, 512, 256,
                                             nullptr, flag, dprj, nullptr, HH, MROWS_D);
  attn_kernel<<<MROWS_D, 256, 0, stream>>>(eprj, dprj, eout, dout, attnWb, attnv, attnvb,
                                           DWT, denseb, flag, enc_len, dec_len, dense_bf);
  // logits = dense @ out_W.T + out_b  (fp32 out)
  gemm_kernel<<<dim3(500,4), 256, 0, stream>>>(dense_bf, nullptr, nullptr, outW, 256, 0,
                                               outb, flag, out, nullptr, OUTV, MROWS_D);
}

// Round 6
// 1285.779 us; speedup vs baseline: 1.3794x; 1.3080x over previous
//
#include <hip/hip_runtime.h>
#include <hip/hip_bf16.h>

typedef unsigned short ushort_t;
typedef unsigned int uint_t;

#define BB 16
#define TE 128
#define TD 64
#define HH 256
#define G3 768
#define KK 256
#define OUTV 32000
#define MROWS_E (BB*TE)   // 2048
#define MROWS_D (BB*TD)   // 1024

typedef __attribute__((ext_vector_type(8))) short short8;
typedef __attribute__((ext_vector_type(4))) float f32x4;

__device__ __forceinline__ float b2f(ushort_t u) {
  union { uint_t i; float f; } v; v.i = ((uint_t)u) << 16; return v.f;
}
__device__ __forceinline__ ushort_t f2b(float f) {
  union { float f; uint_t i; } v; v.f = f;
  uint_t x = v.i;
  return (ushort_t)((x + 0x7fffu + ((x >> 16) & 1u)) >> 16);
}
__device__ __forceinline__ float blo(uint_t u){ union{uint_t i; float f;} v; v.i = u << 16; return v.f; }
__device__ __forceinline__ float bhi(uint_t u){ union{uint_t i; float f;} v; v.i = u & 0xffff0000u; return v.f; }
// dtype-adaptive scalar load of a "float" input: f32f!=0 -> fp32 buffer, else bf16
__device__ __forceinline__ float ldf(const void* p, size_t i, uint_t f32f) {
  return f32f ? ((const float*)p)[i] : b2f(((const ushort_t*)p)[i]);
}
// fast, saturating sigmoid/tanh (inputs bounded; formulas robust at +-inf)
__device__ __forceinline__ float fsig(float x) { return 1.f/(1.f + __expf(-x)); }
__device__ __forceinline__ float ftanh(float x) { return 1.f - 2.f/(__expf(2.f*x) + 1.f); }

// async global->LDS, 16B per lane. Pass per-lane-matching pointers; HW uses
// wave-uniform LDS base + lane*16 (dest must be contiguous in lane order).
__device__ __forceinline__ void gload_lds16(const void* g, void* l) {
  __builtin_amdgcn_global_load_lds(
      (const __attribute__((address_space(1))) unsigned int*)g,
      (__attribute__((address_space(3))) unsigned int*)l, 16, 0, 0);
}

// ---------------------------------------------------------------------------
// dtype detector (round1/2 A/B proved fp32 on this harness; kept for safety).
// ---------------------------------------------------------------------------
__global__ __launch_bounds__(256) void detect_kernel(const void* emb, uint_t* flag) {
  int tid = threadIdx.x;
  uint_t w = ((const uint_t*)emb)[tid];
  uint_t e = (w >> 7) & 0xFFu;
  bool pass = (e >= 100u && e <= 127u);
  unsigned long long m = __ballot(pass);
  __shared__ int cnt[4];
  if ((tid & 63) == 0) cnt[tid >> 6] = __popcll(m);
  __syncthreads();
  if (tid == 0) {
    int c = cnt[0] + cnt[1] + cnt[2] + cnt[3];
    *flag = (c >= 128) ? 0u : 1u;
  }
}

// ---------------------------------------------------------------------------
// prep: Whh -> bf16 row-major [768][256]; dense_W -> bf16 transpose.
// ---------------------------------------------------------------------------
__global__ __launch_bounds__(256) void prep_kernel(
    const void* eWhh, const void* dWhh, const void* denseW,
    const uint_t* flagp, ushort_t* WBe, ushort_t* WBd, ushort_t* DWT) {
  uint_t f = *flagp;
  int tid = blockIdx.x * blockDim.x + threadIdx.x;
  int nth = gridDim.x * blockDim.x;
  for (int i = tid; i < G3*KK; i += nth) {
    WBe[i] = f2b(ldf(eWhh, i, f));
    WBd[i] = f2b(ldf(dWhh, i, f));
  }
  for (int i = tid; i < 512*HH; i += nth) {
    int k = i / HH, c = i % HH;
    DWT[i] = f2b(ldf(denseW, (size_t)c*512 + k, f));
  }
}

// ---------------------------------------------------------------------------
// Generic MFMA GEMM: C[m][n] = sum_k A[m][k]*B[n][k] (+bias[n]), K=256 fixed.
// tshift!=0: output rows remapped m=(b*T+t) -> t*BB+b with T=1<<tshift
// (gives the GRU a (t, batch)-contiguous gi layout for async staging).
// ---------------------------------------------------------------------------
#define LDT 264

__global__ __launch_bounds__(256) void gemm_kernel(
    const ushort_t* A, const int* tokens, const void* emb,
    const void* Bw, int ldb, int b_off,
    const void* bias, const uint_t* flagp,
    float* Cf, ushort_t* Cb, int ldc, int M, int tshift) {
  __shared__ __align__(16) ushort_t Bs[64*LDT];
  __shared__ __align__(16) ushort_t As[32*LDT];
  uint_t f = *flagp;
  int tid = threadIdx.x;
  int wave = tid >> 6, lane = tid & 63;
  int n0 = blockIdx.x * 64;
#pragma unroll
  for (int it = 0; it < 8; ++it) {
    int idx = it*256 + tid;
    int row = idx >> 5, col = (idx & 31) << 3;
    size_t e = (size_t)(n0 + row)*ldb + col + b_off;
    uint4 v;
    if (f) {
      const float4* s = (const float4*)((const float*)Bw + e);
      float4 x = s[0], y = s[1];
      v.x = (uint_t)f2b(x.x) | ((uint_t)f2b(x.y) << 16);
      v.y = (uint_t)f2b(x.z) | ((uint_t)f2b(x.w) << 16);
      v.z = (uint_t)f2b(y.x) | ((uint_t)f2b(y.y) << 16);
      v.w = (uint_t)f2b(y.z) | ((uint_t)f2b(y.w) << 16);
    } else {
      v = *(const uint4*)((const ushort_t*)Bw + e);
    }
    *(uint4*)(Bs + row*LDT + col) = v;
  }
  int arow_i = lane & 15;
  float bias_v = 0.f;
  if (bias) bias_v = ldf(bias, n0 + wave*16 + arow_i, f);
  int koff = (lane >> 4) << 3;
  for (int m0 = blockIdx.y*32; m0 < M; m0 += gridDim.y*32) {
    __syncthreads();   // Bs ready / previous chunk compute done
#pragma unroll
    for (int it = 0; it < 4; ++it) {
      int idx = it*256 + tid;
      int row = idx >> 5, col = (idx & 31) << 3;
      uint4 v;
      if (tokens) {
        size_t e = (size_t)tokens[m0 + row]*KK + col;
        if (f) {
          const float4* s = (const float4*)((const float*)emb + e);
          float4 x = s[0], y = s[1];
          v.x = (uint_t)f2b(x.x) | ((uint_t)f2b(x.y) << 16);
          v.y = (uint_t)f2b(x.z) | ((uint_t)f2b(x.w) << 16);
          v.z = (uint_t)f2b(y.x) | ((uint_t)f2b(y.y) << 16);
          v.w = (uint_t)f2b(y.z) | ((uint_t)f2b(y.w) << 16);
        } else {
          v = *(const uint4*)((const ushort_t*)emb + e);
        }
      } else {
        v = *(const uint4*)(A + (size_t)(m0 + row)*KK + col);  // ws bf16, always
      }
      *(uint4*)(As + row*LDT + col) = v;
    }
    __syncthreads();
#pragma unroll
    for (int msub = 0; msub < 2; ++msub) {
      f32x4 acc = {0.f,0.f,0.f,0.f};
      const ushort_t* ap = As + (msub*16 + arow_i)*LDT + koff;
      const ushort_t* bp = Bs + (wave*16 + arow_i)*LDT + koff;
#pragma unroll
      for (int ks = 0; ks < 8; ++ks) {
        short8 af = *(const short8*)(ap + ks*32);
        short8 bf = *(const short8*)(bp + ks*32);
        acc = __builtin_amdgcn_mfma_f32_16x16x32_bf16(af, bf, acc, 0, 0, 0);
      }
      int mbase = m0 + msub*16 + (lane >> 4)*4;
      int ncol = n0 + wave*16 + arow_i;
#pragma unroll
      for (int r = 0; r < 4; ++r) {
        float val = acc[r] + bias_v;
        int mr = mbase + r;
        int orow = tshift ? (((mr & ((1 << tshift) - 1)) << 4) + (mr >> tshift)) : mr;
        if (Cf) Cf[(size_t)orow*ldc + ncol] = val;
        else    Cb[(size_t)orow*ldc + ncol] = f2b(val);
      }
    }
  }
}

// ---------------------------------------------------------------------------
// MFMA GRU: ONE block, 512 threads (8 waves, 2 waves/SIMD -> 256-VGPR cap).
// Wave w owns hidden cols j in [32w, 32w+32) (two 16-wide tiles) for ALL
// three gates: bfrag = 3*2*8 short8 = 192 VGPRs, truly register-resident.
// h master state in registers (lane owns its 8 (m,j) pairs); h bf16 mirror
// double-buffered in LDS (single barrier/step). gi (fp32, (t,b)-interleaved)
// prefetched one step ahead into an LDS double buffer via global_load_lds;
// the compiler's vmcnt(0) drain before the end-of-step s_barrier gives a
// full step of latency hiding.
// ---------------------------------------------------------------------------
#define HSBF 264            // h_bf row stride (bf16): b128 reads <=2-way banks
#define HBUF (BB*HSBF)      // 4224 shorts = 8448 B per buffer
#define GILDS 772           // gi row stride (fp32): 16B-aligned, <=2-way banks
#define GIBUF (BB*GILDS)    // 12352 floats = 49408 B per buffer

__device__ __forceinline__ void stage_gi(const float* gi, int t, float* sbuf,
                                         int wave, int lane) {
#pragma unroll
  for (int rr = 0; rr < 2; ++rr) {
    int m = wave*2 + rr;
    const float* src = gi + ((size_t)t*BB + m)*G3 + lane*4;
    float* dst = sbuf + m*GILDS + lane*4;
#pragma unroll
    for (int rd = 0; rd < 3; ++rd)
      gload_lds16(src + rd*256, dst + rd*256);
  }
}

__device__ __forceinline__ void gru_phase(
    const float* gi, const ushort_t* WB, const void* bhh, const int* lens,
    uint_t f, int T, float* out, ushort_t* out_bf,
    float* gi_lds, ushort_t* h_bf, float (&hreg)[8], bool init_h)
{
  int tid = threadIdx.x;
  int wave = tid >> 6, lane = tid & 63;
  int mrow = lane & 15, quad = lane >> 4;
  // ---- per-phase setup -------------------------------------------------
  // register-resident Whh fragments: gate g, tile tt -> rows g*256+32w+16tt+mrow
  short8 bfrag[3][2][8];
#pragma unroll
  for (int g = 0; g < 3; ++g)
#pragma unroll
    for (int tt = 0; tt < 2; ++tt) {
      const ushort_t* wb = WB + (size_t)(g*HH + wave*32 + tt*16 + mrow)*KK + (quad << 3);
#pragma unroll
      for (int ks = 0; ks < 8; ++ks)
        bfrag[g][tt][ks] = *(const short8*)(wb + ks*32);
    }
  // biases for this lane's j columns (both tiles), lengths for its 4 m rows
  float bias_r[2], bias_z[2], bias_n[2];
  int len_r[4];
#pragma unroll
  for (int tt = 0; tt < 2; ++tt) {
    int j = wave*32 + tt*16 + mrow;
    bias_r[tt] = ldf(bhh, j, f);
    bias_z[tt] = ldf(bhh, HH + j, f);
    bias_n[tt] = ldf(bhh, 2*HH + j, f);
  }
#pragma unroll
  for (int r = 0; r < 4; ++r) len_r[r] = lens[quad*4 + r];
  if (init_h) {
#pragma unroll
    for (int i = 0; i < 8; ++i) hreg[i] = 0.f;
    for (int i = tid; i < HBUF; i += 512) h_bf[i] = 0;   // buffer 0 only
  }
  stage_gi(gi, 0, gi_lds, wave, lane);
  __syncthreads();   // h_bf[0] + gi buf[0] ready (vmcnt drained by barrier)
  // ---- recurrence ------------------------------------------------------
  for (int t = 0; t < T; ++t) {
    const float* gbuf = gi_lds + (t & 1)*GIBUF;
    float* sbuf = (float*)(gi_lds + ((t + 1) & 1)*GIBUF);
    const ushort_t* hb_r = h_bf + (t & 1)*HBUF;
    ushort_t* hb_w = h_bf + ((t + 1) & 1)*HBUF;
    if (t + 1 < T) stage_gi(gi, t + 1, sbuf, wave, lane);
    f32x4 a00 = {0.f,0.f,0.f,0.f}, a01 = {0.f,0.f,0.f,0.f};
    f32x4 a10 = {0.f,0.f,0.f,0.f}, a11 = {0.f,0.f,0.f,0.f};
    f32x4 a20 = {0.f,0.f,0.f,0.f}, a21 = {0.f,0.f,0.f,0.f};
    const ushort_t* hb = hb_r + mrow*HSBF + (quad << 3);
#pragma unroll
    for (int ks = 0; ks < 8; ++ks) {
      short8 av = *(const short8*)(hb + ks*32);
      a00 = __builtin_amdgcn_mfma_f32_16x16x32_bf16(av, bfrag[0][0][ks], a00, 0, 0, 0);
      a01 = __builtin_amdgcn_mfma_f32_16x16x32_bf16(av, bfrag[0][1][ks], a01, 0, 0, 0);
      a10 = __builtin_amdgcn_mfma_f32_16x16x32_bf16(av, bfrag[1][0][ks], a10, 0, 0, 0);
      a11 = __builtin_amdgcn_mfma_f32_16x16x32_bf16(av, bfrag[1][1][ks], a11, 0, 0, 0);
      a20 = __builtin_amdgcn_mfma_f32_16x16x32_bf16(av, bfrag[2][0][ks], a20, 0, 0, 0);
      a21 = __builtin_amdgcn_mfma_f32_16x16x32_bf16(av, bfrag[2][1][ks], a21, 0, 0, 0);
    }
#pragma unroll
    for (int tt = 0; tt < 2; ++tt) {
      int j = wave*32 + tt*16 + mrow;
#pragma unroll
      for (int r = 0; r < 4; ++r) {
        int m = quad*4 + r;
        const float* gp = gbuf + m*GILDS + j;
        float ar = tt ? a01[r] : a00[r];
        float az = tt ? a11[r] : a10[r];
        float an = tt ? a21[r] : a20[r];
        float rr = fsig(gp[0]    + ar + bias_r[tt]);
        float zz = fsig(gp[HH]   + az + bias_z[tt]);
        float nn = ftanh(gp[2*HH] + rr*(an + bias_n[tt]));
        float hold = hreg[tt*4 + r];
        float hc = (1.f - zz)*nn + zz*hold;
        bool valid = t < len_r[r];
        float ov = valid ? hc : 0.f;
        float hnew = valid ? hc : hold;
        size_t oo = (size_t)(m*T + t)*HH + j;
        out[oo] = ov;
        out_bf[oo] = f2b(ov);
        hreg[tt*4 + r] = hnew;
        hb_w[m*HSBF + j] = f2b(hnew);
      }
    }
    __syncthreads();   // h_bf[1-p] + gi buf for t+1 ready for next step
  }
}

__global__ __launch_bounds__(512, 2) void gru_kernel(
    const float* gi_e, const float* gi_d, const ushort_t* WBe, const ushort_t* WBd,
    const void* ebhh, const void* dbhh, const uint_t* flagp,
    const int* elen, const int* dlen,
    float* eout, float* dout, ushort_t* eout_bf, ushort_t* dout_bf) {
  uint_t f = *flagp;
  __shared__ __align__(16) float gi_lds[2*GIBUF];    // 98816 B
  __shared__ __align__(16) ushort_t h_bf[2*HBUF];    // 16896 B
  float hreg[8];
  gru_phase(gi_e, WBe, ebhh, elen, f, TE, eout, eout_bf, gi_lds, h_bf, hreg, true);
  // TE=128 even -> encoder's final h landed in h_bf buffer 0; decoder reads it.
  gru_phase(gi_d, WBd, dbhh, dlen, f, TD, dout, dout_bf, gi_lds, h_bf, hreg, false);
}

// ---------------------------------------------------------------------------
// Attention + dense, one block per (b, td). (unchanged from round 4/5)
// ---------------------------------------------------------------------------
__global__ __launch_bounds__(256) void attn_kernel(
    const float* eprj, const float* dprj, const float* eout, const float* dout,
    const void* Wb, const void* av, const void* avb,
    const ushort_t* DWT, const void* db, const uint_t* flagp,
    const int* elen, const int* dlen, ushort_t* dense_bf) {
  int bd = blockIdx.x;
  int b = bd / TD, td = bd % TD;
  int tid = threadIdx.x;
  int wave = tid >> 6, lane = tid & 63;
  uint_t f = *flagp;
  __shared__ float dp[HH], dsrow[HH], vv[HH], att[TE];
  int el = elen[b];
  bool dok = td < dlen[b];
  size_t drow = (size_t)bd * HH;
  dp[tid] = dprj[drow + tid] + ldf(Wb, tid, f);
  dsrow[tid] = dout[drow + tid];
  vv[tid] = ldf(av, tid, f);
  __syncthreads();
  float vb0 = ldf(avb, 0, f);
  for (int teb = 0; teb < TE/4; ++teb) {
    int te = teb*4 + wave;
    float e = -1e30f;
    if (dok && te < el) {
      const float* ep = eprj + (size_t)(b*TE + te)*HH;
      float s = 0.f;
#pragma unroll
      for (int i = 0; i < 4; ++i) {
        int hh = lane + 64*i;
        s += tanhf(ep[hh] + dp[hh]) * vv[hh];
      }
#pragma unroll
      for (int off = 32; off > 0; off >>= 1) s += __shfl_xor(s, off);
      e = s + vb0;
    }
    if (lane == 0) att[te] = e;
  }
  __syncthreads();
  float m = -1e30f;
  for (int te = 0; te < TE; ++te) m = fmaxf(m, att[te]);
  __syncthreads();
  if (tid < TE) {
    float e = att[tid];
    att[tid] = (e > -1e29f) ? expf(e - m) : 0.f;
  }
  __syncthreads();
  float ssum = 0.f;
  for (int te = 0; te < TE; ++te) ssum += att[te];
  float inv = (ssum > 0.f) ? 1.f/ssum : 0.f;
  float c = 0.f;
  for (int te = 0; te < TE; ++te) {
    float wgt = att[te];
    if (wgt > 0.f) c += wgt * eout[(size_t)(b*TE + te)*HH + tid];
  }
  c *= inv;
  __syncthreads();
  dp[tid] = c;   // reuse dp as context
  __syncthreads();
  float acc = ldf(db, tid, f);
#pragma unroll 4
  for (int k = 0; k < HH; ++k) acc = fmaf(b2f(DWT[k*HH + tid]), dsrow[k], acc);
#pragma unroll 4
  for (int k = 0; k < HH; ++k) acc = fmaf(b2f(DWT[(HH + k)*HH + tid]), dp[k], acc);
  dense_bf[drow + tid] = f2b(tanhf(acc));
}

// ---------------------------------------------------------------------------
extern "C" void kernel_launch(void* const* d_in, const int* in_sizes, int n_in,
                              void* d_out, int out_size, void* d_ws, size_t ws_size,
                              hipStream_t stream) {
  const int* enc_in   = (const int*)d_in[0];
  const int* enc_len  = (const int*)d_in[1];
  const int* dec_in   = (const int*)d_in[2];
  const int* dec_len  = (const int*)d_in[3];
  const void* emb    = d_in[4];
  const void* eWih   = d_in[5];
  const void* eWhh   = d_in[6];
  const void* ebih   = d_in[7];
  const void* ebhh   = d_in[8];
  const void* dWih   = d_in[9];
  const void* dWhh   = d_in[10];
  const void* dbih   = d_in[11];
  const void* dbhh   = d_in[12];
  const void* attnW  = d_in[13];
  const void* attnWb = d_in[14];
  const void* attnv  = d_in[15];
  const void* attnvb = d_in[16];
  const void* denseW = d_in[17];
  const void* denseb = d_in[18];
  const void* outW   = d_in[19];
  const void* outb   = d_in[20];
  float* out = (float*)d_out;   // reference output is fp32

  float* ws = (float*)d_ws;
  size_t o = 0;
  uint_t* flag = (uint_t*)(ws + o);   o += 4;
  ushort_t* WBe = (ushort_t*)(ws + o); o += G3*KK/2;
  ushort_t* WBd = (ushort_t*)(ws + o); o += G3*KK/2;
  ushort_t* DWT = (ushort_t*)(ws + o); o += 512*HH/2;
  float* gi_e = ws + o;               o += (size_t)MROWS_E*G3;   // (t,b)-interleaved
  float* gi_d = ws + o;               o += (size_t)MROWS_D*G3;   // (t,b)-interleaved
  float* eout = ws + o;               o += (size_t)MROWS_E*HH;
  float* dout = ws + o;               o += (size_t)MROWS_D*HH;
  ushort_t* eout_bf = (ushort_t*)(ws + o); o += (size_t)MROWS_E*HH/2;
  ushort_t* dout_bf = (ushort_t*)(ws + o); o += (size_t)MROWS_D*HH/2;
  float* eprj = ws + o;               o += (size_t)MROWS_E*HH;
  float* dprj = ws + o;               o += (size_t)MROWS_D*HH;
  ushort_t* dense_bf = (ushort_t*)(ws + o); o += (size_t)MROWS_D*HH/2;

  detect_kernel<<<1, 256, 0, stream>>>(emb, flag);
  prep_kernel<<<384, 256, 0, stream>>>(eWhh, dWhh, denseW, flag, WBe, WBd, DWT);
  // gi = emb[tokens] @ Wih.T + bih, rows written (t,b)-interleaved for the GRU
  gemm_kernel<<<dim3(12,8), 256, 0, stream>>>(nullptr, enc_in, emb, eWih, 256, 0,
                                              ebih, flag, gi_e, nullptr, G3, MROWS_E, 7);
  gemm_kernel<<<dim3(12,4), 256, 0, stream>>>(nullptr, dec_in, emb, dWih, 256, 0,
                                              dbih, flag, gi_d, nullptr, G3, MROWS_D, 6);
  gru_kernel<<<1, 512, 0, stream>>>(gi_e, gi_d, WBe, WBd, ebhh, dbhh, flag,
                                    enc_len, dec_len, eout, dout, eout_bf, dout_bf);
  // enc_proj = enc_out @ W1.T ; dec_proj = dec_out @ W2.T  (attn_W col split)
  gemm_kernel<<<dim3(4,16), 256, 0, stream>>>(eout_bf, nullptr, nullptr, attnW, 512, 0,
                                              nullptr, flag, eprj, nullptr, HH, MROWS_E, 0);
  gemm_kernel<<<dim3(4,8), 256, 0, stream>>>(dout_bf, nullptr, nullptr, attnW, 512, 256,
                                             nullptr, flag, dprj, nullptr, HH, MROWS_D, 0);
  attn_kernel<<<MROWS_D, 256, 0, stream>>>(eprj, dprj, eout, dout, attnWb, attnv, attnvb,
                                           DWT, denseb, flag, enc_len, dec_len, dense_bf);
  // logits = dense @ out_W.T + out_b  (fp32 out)
  gemm_kernel<<<dim3(500,4), 256, 0, stream>>>(dense_bf, nullptr, nullptr, outW, 256, 0,
                                               outb, flag, out, nullptr, OUTV, MROWS_D, 0);
}